// Round 8
// baseline (193.172 us; speedup 1.0000x reference)
//
#include <hip/hip_runtime.h>

#define TT 48
#define DD 32
#define HH 64
#define BB 16384

typedef __bf16 bf16x8 __attribute__((ext_vector_type(8)));
typedef float f32x4 __attribute__((ext_vector_type(4)));

#define MFMA(a, b, c) __builtin_amdgcn_mfma_f32_16x16x32_bf16(a, b, c, 0, 0, 0)
#define BC(v) __builtin_bit_cast(bf16x8, v)

static __device__ __forceinline__ unsigned short bfu(float f) {
  __bf16 b = (__bf16)f;
  return __builtin_bit_cast(unsigned short, b);
}
static __device__ __forceinline__ float bff(unsigned short u) {
  return (float)__builtin_bit_cast(__bf16, u);
}
static __device__ __forceinline__ __bf16 bfc(unsigned short u) {
  return __builtin_bit_cast(__bf16, u);
}
static __device__ __forceinline__ float sigm(float v) {
  return __builtin_amdgcn_rcpf(1.f + __expf(-v));
}
static __device__ __forceinline__ float tanh_f(float v) {
  // 1 - 2/(1+e^{2x}); saturates correctly at +-inf
  return fmaf(-2.f, __builtin_amdgcn_rcpf(1.f + __expf(2.f * v)), 1.f);
}

// ------------------------------------------------------------------
// Row bijection: tile m = g*4+hq (g = gate), tile-row = qp*4+r.
//   hidx(hq,qp,r) = (hq>>1)*32 + qp*8 + (hq&1)*4 + r
// Lane (b,qp)'s D outputs == exactly its next-step B-fragment slots ->
// h never leaves the lane: zero LDS/shuffle in the recurrence.
// ------------------------------------------------------------------

// Kernel 0: linearize W into per-lane MFMA A-fragment order with the bijection.
__global__ void prep_kernel(const float* __restrict__ W_ih, const float* __restrict__ W_hh,
                            const float* __restrict__ b_ih, const float* __restrict__ b_hh,
                            unsigned short* __restrict__ WhhL, unsigned short* __restrict__ WihL,
                            float* __restrict__ bsumL) {
  const int tid = threadIdx.x;  // 256 threads, 1 block
  const int l = tid & 63, qt = tid >> 6;
  const int rowl = l & 15, kq = (l >> 4) * 8;
  for (int mm = 0; mm < 4; ++mm) {
    const int m = qt * 4 + mm;
    const int g = m >> 2, hq = m & 3;
    const int hidx = (hq >> 1) * 32 + (rowl >> 2) * 8 + (hq & 1) * 4 + (rowl & 3);
    const int orig = g * 64 + hidx;
    for (int c = 0; c < 2; ++c)
      for (int j = 0; j < 8; ++j) {
        float w = W_hh[orig * 64 + c * 32 + kq + j];
        unsigned short hi = bfu(w);
        WhhL[((0 * 16 + m) * 2 + c) * 512 + l * 8 + j] = hi;
        WhhL[((1 * 16 + m) * 2 + c) * 512 + l * 8 + j] = bfu(w - bff(hi));
      }
    for (int j = 0; j < 8; ++j)
      WihL[m * 512 + l * 8 + j] = bfu(W_ih[orig * 32 + kq + j]);
    if ((l >> 4) == 0) bsumL[m * 16 + rowl] = b_ih[orig] + b_hh[orig];
  }
}

// ------------------------------------------------------------------
// Kernel 1: attention. a[b,:] = softmax_d( sum_t x[b,t,d]*w_att[2H+t] )
// (h/c/b_att terms are uniform over d -> softmax-invariant -> dropped).
// ------------------------------------------------------------------
__global__ __launch_bounds__(256) void attn_kernel(const float* __restrict__ x,
                                                   const float* __restrict__ W_att,
                                                   float* __restrict__ out0) {
  int tid = threadIdx.x;
  int b = blockIdx.x * 32 + (tid >> 3);
  int dq = (tid & 7) * 4;
  const float* xb = x + (size_t)b * (TT * DD);
  float px = 0.f, py = 0.f, pz = 0.f, pw = 0.f;
#pragma unroll 4
  for (int t = 0; t < TT; ++t) {
    float w = W_att[2 * HH + t];
    float4 xv = *(const float4*)(xb + t * DD + dq);
    px = fmaf(xv.x, w, px);
    py = fmaf(xv.y, w, py);
    pz = fmaf(xv.z, w, pz);
    pw = fmaf(xv.w, w, pw);
  }
  float m = fmaxf(fmaxf(px, py), fmaxf(pz, pw));
#pragma unroll
  for (int s = 1; s < 8; s <<= 1) m = fmaxf(m, __shfl_xor(m, s));
  float ex = __expf(px - m), ey = __expf(py - m), ez = __expf(pz - m), ew = __expf(pw - m);
  float sum = ex + ey + ez + ew;
#pragma unroll
  for (int s = 1; s < 8; s <<= 1) sum += __shfl_xor(sum, s);
  float inv = __builtin_amdgcn_rcpf(sum);
  float4 a;
  a.x = ex * inv; a.y = ey * inv; a.z = ez * inv; a.w = ew * inv;
  float* o = out0 + (size_t)b * (TT * DD) + dq;
#pragma unroll 4
  for (int t = 0; t < TT; ++t) *(float4*)(o + t * DD) = a;
}

// ------------------------------------------------------------------
// Kernel 2: lane-local register-resident LSTM with PINNED weights.
// 256 blocks x 256 thr; each wave owns 16 batch rows end-to-end, no
// LDS/shuffle/barrier in the T loop. Weights pinned via empty asm
// ("+v") so the compiler cannot rematerialize the loads inside the
// loop (round 6/7 showed VGPR=192 => ~80KB/wave/step of L2 reloads).
// Split precision: Whi*Bhi + Wlo*Bhi + Whi*Blo per 32-chunk.
// ------------------------------------------------------------------
__global__ __launch_bounds__(256, 1) void lstm_kernel(
    const float* __restrict__ x, const float* __restrict__ h0, const float* __restrict__ c0,
    const float* __restrict__ a_src, const unsigned short* __restrict__ WhhL,
    const unsigned short* __restrict__ WihL, const float* __restrict__ bsumL,
    float* __restrict__ out1) {
  __shared__ __align__(16) float sbias[256];
  const int tid = threadIdx.x;
  const int l = tid & 63;
  const int wid = tid >> 6;
  const int b = l & 15;
  const int qp = l >> 4;
  const int brow = blockIdx.x * 64 + wid * 16 + b;

  sbias[tid] = bsumL[tid];

  // resident W fragments (f32x4 carriers; bitcast to bf16x8 at use)
  f32x4 whh[2][16][2];
#pragma unroll
  for (int p = 0; p < 2; ++p)
#pragma unroll
    for (int m = 0; m < 16; ++m)
#pragma unroll
      for (int c = 0; c < 2; ++c)
        whh[p][m][c] = *(const f32x4*)(WhhL + (((p * 16 + m) * 2 + c) << 9) + l * 8);
  f32x4 wih[16];
#pragma unroll
  for (int m = 0; m < 16; ++m)
    wih[m] = *(const f32x4*)(WihL + (m << 9) + l * 8);

  // PIN: make values asm-outputs -> rematerialization of the loads is illegal
#pragma unroll
  for (int p = 0; p < 2; ++p)
#pragma unroll
    for (int m = 0; m < 16; ++m)
#pragma unroll
      for (int c = 0; c < 2; ++c)
        asm volatile("" : "+v"(whh[p][m][c]));
#pragma unroll
  for (int m = 0; m < 16; ++m) asm volatile("" : "+v"(wih[m]));

  // attention weights for this lane's B-fragment slots (d = qp*8 + j)
  float av[8];
  {
    const float* ap = a_src + (size_t)brow * (TT * DD) + qp * 8;
    float4 a0 = *(const float4*)ap, a1 = *(const float4*)(ap + 4);
    av[0] = a0.x; av[1] = a0.y; av[2] = a0.z; av[3] = a0.w;
    av[4] = a1.x; av[5] = a1.y; av[6] = a1.z; av[7] = a1.w;
  }

  // c state: creg[hq][r] = c[brow][hidx(hq,qp,r)]
  f32x4 creg[4];
#pragma unroll
  for (int hq = 0; hq < 4; ++hq)
    creg[hq] = *(const f32x4*)(c0 + (size_t)brow * HH + (hq >> 1) * 32 + qp * 8 + (hq & 1) * 4);

  // h state as B-fragments: bh[c][p] elem j = split_p(h[brow][c*32+qp*8+j])
  bf16x8 bh[2][2];
#pragma unroll
  for (int c = 0; c < 2; ++c) {
    const float* hp = h0 + (size_t)brow * HH + c * 32 + qp * 8;
    float4 v0 = *(const float4*)hp, v1 = *(const float4*)(hp + 4);
    float vv[8] = {v0.x, v0.y, v0.z, v0.w, v1.x, v1.y, v1.z, v1.w};
#pragma unroll
    for (int j = 0; j < 8; ++j) {
      unsigned short hi = bfu(vv[j]);
      bh[c][0][j] = bfc(hi);
      bh[c][1][j] = bfc(bfu(vv[j] - bff(hi)));
    }
  }
  __syncthreads();  // only for sbias staging

  const float* xp = x + (size_t)brow * (TT * DD) + qp * 8;
  float* op = out1 + (size_t)brow * (TT * HH);
  float xv[8];
  {
    float4 x0 = *(const float4*)xp, x1 = *(const float4*)(xp + 4);
    xv[0] = x0.x; xv[1] = x0.y; xv[2] = x0.z; xv[3] = x0.w;
    xv[4] = x1.x; xv[5] = x1.y; xv[6] = x1.z; xv[7] = x1.w;
  }

  for (int t = 0; t < TT; ++t) {
    // B-frag: xw = a*x (single bf16; lo-correction negligible at |a*x|~0.03)
    bf16x8 bxw;
#pragma unroll
    for (int j = 0; j < 8; ++j) bxw[j] = (__bf16)(xv[j] * av[j]);
    // prefetch next x
    float xn[8];
    if (t + 1 < TT) {
      const float* xnp = xp + (t + 1) * DD;
      float4 x0 = *(const float4*)xnp, x1 = *(const float4*)(xnp + 4);
      xn[0] = x0.x; xn[1] = x0.y; xn[2] = x0.z; xn[3] = x0.w;
      xn[4] = x1.x; xn[5] = x1.y; xn[6] = x1.z; xn[7] = x1.w;
    }

    bf16x8 nbh[2][2];
#pragma unroll
    for (int hq = 0; hq < 4; ++hq) {
      f32x4 acc[4];
#pragma unroll
      for (int g = 0; g < 4; ++g) {
        const int m = g * 4 + hq;
        f32x4 A = *(const f32x4*)(sbias + m * 16 + qp * 4);  // broadcast, conflict-free
        A = MFMA(BC(whh[0][m][0]), bh[0][0], A);  // k 0..31: Whi*Bhi
        A = MFMA(BC(whh[1][m][0]), bh[0][0], A);  //          Wlo*Bhi
        A = MFMA(BC(whh[0][m][0]), bh[0][1], A);  //          Whi*Blo
        A = MFMA(BC(whh[0][m][1]), bh[1][0], A);  // k 32..63
        A = MFMA(BC(whh[1][m][1]), bh[1][0], A);
        A = MFMA(BC(whh[0][m][1]), bh[1][1], A);
        A = MFMA(BC(wih[m]), bxw, A);             // input chunk
        acc[g] = A;
      }
      // pointwise: i/f/g/o lane-local (rows qp*4+r of tiles g*4+hq)
      float hr[4];
#pragma unroll
      for (int r = 0; r < 4; ++r) {
        float ig = sigm(acc[0][r]);
        float fg = sigm(acc[1][r]);
        float gt = tanh_f(acc[2][r]);
        float og = sigm(acc[3][r]);
        float cn = fg * creg[hq][r] + ig * gt;
        creg[hq][r] = cn;
        hr[r] = og * tanh_f(cn);
      }
      // out1: contiguous float4 at hidx base (4 qp-lanes cover the full row)
      float4 hv;
      hv.x = hr[0]; hv.y = hr[1]; hv.z = hr[2]; hv.w = hr[3];
      *(float4*)(op + (size_t)t * HH + (hq >> 1) * 32 + qp * 8 + (hq & 1) * 4) = hv;
      // repack into next step's B-fragment (lane-local, no exchange)
#pragma unroll
      for (int r = 0; r < 4; ++r) {
        unsigned short hb = bfu(hr[r]);
        nbh[hq >> 1][0][(hq & 1) * 4 + r] = bfc(hb);
        nbh[hq >> 1][1][(hq & 1) * 4 + r] = bfc(bfu(hr[r] - bff(hb)));
      }
    }
#pragma unroll
    for (int c = 0; c < 2; ++c) {
      bh[c][0] = nbh[c][0];
      bh[c][1] = nbh[c][1];
    }
#pragma unroll
    for (int j = 0; j < 8; ++j) xv[j] = xn[j];
  }
}

extern "C" void kernel_launch(void* const* d_in, const int* in_sizes, int n_in,
                              void* d_out, int out_size, void* d_ws, size_t ws_size,
                              hipStream_t stream) {
  const float* x = (const float*)d_in[0];
  const float* h0 = (const float*)d_in[1];
  const float* c0 = (const float*)d_in[2];
  const float* W_att = (const float*)d_in[3];
  // d_in[4] = b_att: uniform shift, softmax-invariant -> unused
  const float* W_ih = (const float*)d_in[5];
  const float* W_hh = (const float*)d_in[6];
  const float* b_ih = (const float*)d_in[7];
  const float* b_hh = (const float*)d_in[8];

  float* out0 = (float*)d_out;                // attention [B,T,D]
  float* out1 = out0 + (size_t)BB * TT * DD;  // input_encoded [B,T,H]

  char* ws = (char*)d_ws;
  unsigned short* WhhL = (unsigned short*)ws;            // 65536 B
  unsigned short* WihL = (unsigned short*)(ws + 65536);  // 16384 B
  float* bsumL = (float*)(ws + 81920);                   // 1024 B

  prep_kernel<<<1, 256, 0, stream>>>(W_ih, W_hh, b_ih, b_hh, WhhL, WihL, bsumL);
  attn_kernel<<<BB / 32, 256, 0, stream>>>(x, W_att, out0);
  // lstm reads a[b,d] from the t=0 slice of out0 (== a broadcast over t)
  lstm_kernel<<<BB / 64, 256, 0, stream>>>(x, h0, c0, out0, WhhL, WihL, bsumL, out1);
}